// Round 1
// 283.579 us; speedup vs baseline: 1.1680x; 1.1680x over previous
//
#include <hip/hip_runtime.h>
#include <math.h>

// GCN-VGAE encoder, N=100000 nodes, E=1600000 edges, F=H=128, O=64 (fp32 in/out).
// Strategy:
//   - CSR build is now a two-level ATOMIC-FREE radix partition (global atomics on
//     gfx950 write through to the coherent point at 32B/op = 51MB fabric traffic;
//     normal stores are L2-absorbed). Coarse partition by col>>8 with LDS cursors,
//     then per-bucket fine CSR build entirely in LDS. Rank order within a node is
//     arbitrary (same nondeterminism class as the old atomic ranks).
//   - Symmetric norm factored: pre-scale rows by dinv, aggregate with RAW edge
//     weights, post-scale by dinv[c]. deg computed atomic-free from CSR segments.
//   - Gathered feature matrices stored in bf16 (halves L3-bound gather traffic).
//   - GEMMs on MFMA (16x16x32 bf16) with SPLIT precision: A=Ahi+Alo, W=Whi+Wlo,
//     C = Ahi*Whi + Alo*Whi + Ahi*Wlo  (error ~2^-18, fp32-grade).
//   - conv2/conv3 fused: agg2 = A_norm @ h once, then one GEMM with [Wmu|Wls].

#define NBLK 1024   // coarse-partition blocks; each handles ceil(E/NBLK) edges

typedef __attribute__((ext_vector_type(8))) short bf16x8;
typedef __attribute__((ext_vector_type(4))) float f32x4;

__device__ __forceinline__ unsigned short f2bf_rne(float f) {
  unsigned int u = __float_as_uint(f);
  u += 0x7FFFu + ((u >> 16) & 1u);
  return (unsigned short)(u >> 16);
}

__device__ __forceinline__ float bf2f(unsigned short h) {
  return __uint_as_float(((unsigned int)h) << 16);
}

__device__ __forceinline__ unsigned int pack2(unsigned short a, unsigned short b) {
  return (unsigned int)a | ((unsigned int)b << 16);
}

// ---------------- CSR build: two-level atomic-free partition ----------------

// Per-block LDS histogram over coarse buckets (col>>8). G[bucket][blk] layout.
__global__ __launch_bounds__(256) void hist_coarse(const int* __restrict__ col,
                                                   int* __restrict__ G,
                                                   int E, int nbuck, int epb) {
  __shared__ int h[512];
  int blk = blockIdx.x;
  for (int i = threadIdx.x; i < nbuck; i += 256) h[i] = 0;
  __syncthreads();
  int beg = blk * epb;
  int end = min(beg + epb, E);
  for (int p = beg + threadIdx.x; p < end; p += 256)
    atomicAdd(&h[col[p] >> 8], 1);
  __syncthreads();
  for (int i = threadIdx.x; i < nbuck; i += 256)
    G[(size_t)i * NBLK + blk] = h[i];
}

// Per-bucket exclusive scan over the NBLK block-counts; emits bucket totals.
__global__ __launch_bounds__(1024) void scan_bucket(int* __restrict__ G,
                                                    int* __restrict__ tot) {
  __shared__ int s[NBLK];
  int b = blockIdx.x;
  int v = G[(size_t)b * NBLK + threadIdx.x];
  s[threadIdx.x] = v;
  __syncthreads();
  for (int off = 1; off < NBLK; off <<= 1) {
    int t = (threadIdx.x >= off) ? s[threadIdx.x - off] : 0;
    __syncthreads();
    s[threadIdx.x] += t;
    __syncthreads();
  }
  G[(size_t)b * NBLK + threadIdx.x] = s[threadIdx.x] - v;   // exclusive
  if (threadIdx.x == NBLK - 1) tot[b] = s[NBLK - 1];
}

// Exclusive scan of bucket totals -> start[0..nbuck] (start[nbuck]=E).
__global__ __launch_bounds__(512) void scan_start(const int* __restrict__ tot,
                                                  int* __restrict__ start,
                                                  int* __restrict__ row_ptr,
                                                  int nbuck, int N, int E) {
  __shared__ int s[512];
  int v = (threadIdx.x < nbuck) ? tot[threadIdx.x] : 0;
  s[threadIdx.x] = v;
  __syncthreads();
  for (int off = 1; off < 512; off <<= 1) {
    int t = (threadIdx.x >= off) ? s[threadIdx.x - off] : 0;
    __syncthreads();
    s[threadIdx.x] += t;
    __syncthreads();
  }
  if (threadIdx.x < nbuck) start[threadIdx.x] = s[threadIdx.x] - v;
  if (threadIdx.x == 511) start[nbuck] = s[511];   // == E
  if (threadIdx.x == 0) row_ptr[N] = E;
}

// Coarse scatter: LDS cursors (start[b] + G[b][blk]); packs row|colLow into .x.
// All writes are plain stores (L2 write-back) — zero global atomics.
__global__ __launch_bounds__(256) void partition_edges(
    const int* __restrict__ row, const int* __restrict__ col,
    const float* __restrict__ w, const int* __restrict__ G,
    const int* __restrict__ start, int2* __restrict__ part,
    int E, int nbuck, int epb) {
  __shared__ int cur[512];
  int blk = blockIdx.x;
  for (int i = threadIdx.x; i < nbuck; i += 256)
    cur[i] = start[i] + G[(size_t)i * NBLK + blk];
  __syncthreads();
  int beg = blk * epb;
  int end = min(beg + epb, E);
  for (int p = beg + threadIdx.x; p < end; p += 256) {
    int c = col[p];
    int pos = atomicAdd(&cur[c >> 8], 1);             // LDS atomic
    part[pos] = make_int2(row[p] | ((c & 255) << 17), // row < 2^17
                          __float_as_int(w[p]));
  }
}

// Fine build: one block per bucket (256 nodes). LDS hist + scan -> row_ptr and
// exact CSR slots; final writes stay inside the bucket's ~32KB window.
__global__ __launch_bounds__(256) void build_fine(const int* __restrict__ start,
                                                  const int2* __restrict__ part,
                                                  int* __restrict__ row_ptr,
                                                  int2* __restrict__ csr,
                                                  int N) {
  __shared__ int hist[256];
  __shared__ int sc[256];
  __shared__ int cur[256];
  int b = blockIdx.x;
  int ebeg = start[b], eend = start[b + 1];
  hist[threadIdx.x] = 0;
  __syncthreads();
  for (int p = ebeg + threadIdx.x; p < eend; p += 256)
    atomicAdd(&hist[(part[p].x >> 17) & 255], 1);
  __syncthreads();
  int v = hist[threadIdx.x];
  sc[threadIdx.x] = v;
  __syncthreads();
  for (int off = 1; off < 256; off <<= 1) {
    int t = (threadIdx.x >= off) ? sc[threadIdx.x - off] : 0;
    __syncthreads();
    sc[threadIdx.x] += t;
    __syncthreads();
  }
  int ex = sc[threadIdx.x] - v;   // exclusive
  int node = b * 256 + threadIdx.x;
  if (node < N) row_ptr[node] = ebeg + ex;
  cur[threadIdx.x] = ebeg + ex;
  __syncthreads();
  for (int p = ebeg + threadIdx.x; p < eend; p += 256) {
    int2 r = part[p];
    int cl = (r.x >> 17) & 255;
    int pos = atomicAdd(&cur[cl], 1);                 // LDS atomic
    csr[pos] = make_int2(r.x & 0x1FFFF, r.y);
  }
}

// deg[c] = 1 (self-loop) + sum of raw weights over CSR segment; dinv = 1/sqrt.
__global__ void deg_dinv(const int* __restrict__ row_ptr, const int2* __restrict__ csr,
                         float* __restrict__ dinv, int n) {
  int i = blockIdx.x * blockDim.x + threadIdx.x;
  if (i >= n) return;
  float s = 1.0f;
  int end = row_ptr[i + 1];
  for (int p = row_ptr[i]; p < end; ++p) s += __int_as_float(csr[p].y);
  dinv[i] = 1.0f / sqrtf(s);
}

// Transpose + bf16-split a 128x128 fp32 W: wt_hi/wt_lo[n][k] = split(W[k][n]).
__global__ void prep_wt(const float* __restrict__ Wsrc,
                        unsigned short* __restrict__ wt_hi,
                        unsigned short* __restrict__ wt_lo) {
  int i = blockIdx.x * blockDim.x + threadIdx.x;
  if (i >= 128 * 128) return;
  int n = i & 127, k = i >> 7;
  float f = Wsrc[(size_t)k * 128 + n];
  unsigned short h = f2bf_rne(f);
  unsigned short l = f2bf_rne(f - bf2f(h));
  wt_hi[(size_t)n * 128 + k] = h;
  wt_lo[(size_t)n * 128 + k] = l;
}

// Same for concatenated [Wmu | Wls] (each 128x64), plus bias concat.
__global__ void prep_wcat_t(const float* __restrict__ Wmu, const float* __restrict__ Wls,
                            const float* __restrict__ bmu, const float* __restrict__ bls,
                            unsigned short* __restrict__ wt_hi,
                            unsigned short* __restrict__ wt_lo,
                            float* __restrict__ bcat) {
  int i = blockIdx.x * blockDim.x + threadIdx.x;
  if (i >= 128 * 128) return;
  int n = i & 127, k = i >> 7;
  float f = (n < 64) ? Wmu[(size_t)k * 64 + n] : Wls[(size_t)k * 64 + (n - 64)];
  unsigned short h = f2bf_rne(f);
  unsigned short l = f2bf_rne(f - bf2f(h));
  wt_hi[(size_t)n * 128 + k] = h;
  wt_lo[(size_t)n * 128 + k] = l;
  if (i < 128) bcat[i] = (i < 64) ? bmu[i] : bls[i - 64];
}

// C[M,128] = (A[M,128] @ W[128,128]) * rowscale[row] + bias, via split-bf16 MFMA.
// WtHi/WtLo are bf16, TRANSPOSED [n][k]. Block: 256 thr = 4 waves, C-tile 128x128,
// wave computes 64x64 (4x4 tiles of 16x16). LDS XOR-swizzle: slot ^ (row&7).
// Output: fp32 split (C0 cols<split, C1 rest) and/or bf16 mirror Cbf (stride 128).
__global__ __launch_bounds__(256) void gemm_mfma(
    const float* __restrict__ A,
    const unsigned short* __restrict__ WtHi, const unsigned short* __restrict__ WtLo,
    const float* __restrict__ bias, const float* __restrict__ rowscale,
    float* __restrict__ C0, float* __restrict__ C1,
    unsigned short* __restrict__ Cbf, int split, int M) {
  __shared__ uint4 sAhi[1024];   // [row 0..127][slot 0..7] 16B slots, swizzled
  __shared__ uint4 sAlo[1024];
  __shared__ uint4 sWhi[1024];   // [col 0..127][slot 0..7]
  __shared__ uint4 sWlo[1024];

  int tid = threadIdx.x;
  int lane = tid & 63, wid = tid >> 6;
  int wave_r = (wid >> 1) * 64, wave_c = (wid & 1) * 64;
  int lrow = lane & 15, lkb = lane >> 4;   // lkb = k-chunk 0..3
  int rowBase = blockIdx.x * 128;

  f32x4 acc[4][4];
#pragma unroll
  for (int mr = 0; mr < 4; ++mr)
#pragma unroll
    for (int nc = 0; nc < 4; ++nc) acc[mr][nc] = (f32x4){0.f, 0.f, 0.f, 0.f};

  const uint4* WtHi4 = (const uint4*)WtHi;   // row = 16 uint4 (128 bf16)
  const uint4* WtLo4 = (const uint4*)WtLo;

  for (int kt = 0; kt < 128; kt += 64) {
    __syncthreads();
    // stage W tile: 128 cols x 64 k (bf16, already split) -> swizzled LDS
#pragma unroll
    for (int j = 0; j < 4; ++j) {
      int g = tid + 256 * j;            // 0..1023
      int c = g >> 3, k8 = g & 7;
      int slot = k8 ^ (c & 7);
      sWhi[c * 8 + slot] = WtHi4[c * 16 + (kt >> 3) + k8];
      sWlo[c * 8 + slot] = WtLo4[c * 16 + (kt >> 3) + k8];
    }
    // stage A tile: 128 rows x 64 k fp32 -> split hi/lo bf16 -> swizzled LDS
#pragma unroll
    for (int j = 0; j < 4; ++j) {
      int g = tid + 256 * j;            // 0..1023
      int r = g >> 3, k8 = g & 7;
      int grow = rowBase + r;
      float4 v0 = make_float4(0.f, 0.f, 0.f, 0.f);
      float4 v1 = v0;
      if (grow < M) {
        const float4* Ar = (const float4*)(A + (size_t)grow * 128 + kt);
        v0 = Ar[k8 * 2];
        v1 = Ar[k8 * 2 + 1];
      }
      float f[8] = {v0.x, v0.y, v0.z, v0.w, v1.x, v1.y, v1.z, v1.w};
      unsigned short h[8], l[8];
#pragma unroll
      for (int q = 0; q < 8; ++q) {
        h[q] = f2bf_rne(f[q]);
        l[q] = f2bf_rne(f[q] - bf2f(h[q]));
      }
      int slot = k8 ^ (r & 7);
      sAhi[r * 8 + slot] = make_uint4(pack2(h[0], h[1]), pack2(h[2], h[3]),
                                      pack2(h[4], h[5]), pack2(h[6], h[7]));
      sAlo[r * 8 + slot] = make_uint4(pack2(l[0], l[1]), pack2(l[2], l[3]),
                                      pack2(l[4], l[5]), pack2(l[6], l[7]));
    }
    __syncthreads();
    // compute: 2 MFMA k-steps (K=32 each) per LDS tile
#pragma unroll
    for (int ks = 0; ks < 2; ++ks) {
      bf16x8 ah[4], al[4], bh[4], bl[4];
#pragma unroll
      for (int mr = 0; mr < 4; ++mr) {
        int r = wave_r + mr * 16 + lrow;
        int slot = (ks * 4 + lkb) ^ (r & 7);
        ah[mr] = *(const bf16x8*)&sAhi[r * 8 + slot];
        al[mr] = *(const bf16x8*)&sAlo[r * 8 + slot];
      }
#pragma unroll
      for (int nc = 0; nc < 4; ++nc) {
        int c = wave_c + nc * 16 + lrow;
        int slot = (ks * 4 + lkb) ^ (c & 7);
        bh[nc] = *(const bf16x8*)&sWhi[c * 8 + slot];
        bl[nc] = *(const bf16x8*)&sWlo[c * 8 + slot];
      }
#pragma unroll
      for (int mr = 0; mr < 4; ++mr)
#pragma unroll
        for (int nc = 0; nc < 4; ++nc) {
          acc[mr][nc] = __builtin_amdgcn_mfma_f32_16x16x32_bf16(
              ah[mr], bh[nc], acc[mr][nc], 0, 0, 0);
          acc[mr][nc] = __builtin_amdgcn_mfma_f32_16x16x32_bf16(
              al[mr], bh[nc], acc[mr][nc], 0, 0, 0);
          acc[mr][nc] = __builtin_amdgcn_mfma_f32_16x16x32_bf16(
              ah[mr], bl[nc], acc[mr][nc], 0, 0, 0);
        }
    }
  }

  // epilogue: D[row=(lane>>4)*4+reg][col=lane&15] per 16x16 tile
#pragma unroll
  for (int mr = 0; mr < 4; ++mr) {
    int Rb = rowBase + wave_r + mr * 16 + lkb * 4;
    float sc[4];
#pragma unroll
    for (int reg = 0; reg < 4; ++reg)
      sc[reg] = (rowscale && (Rb + reg) < M) ? rowscale[Rb + reg] : 1.0f;
#pragma unroll
    for (int nc = 0; nc < 4; ++nc) {
      int c = wave_c + nc * 16 + lrow;
      float bb = bias ? bias[c] : 0.f;
      f32x4 v = acc[mr][nc];
#pragma unroll
      for (int reg = 0; reg < 4; ++reg) {
        int R = Rb + reg;
        if (R >= M) continue;
        float val = v[reg] * sc[reg] + bb;
        if (Cbf) Cbf[(size_t)R * 128 + c] = f2bf_rne(val);
        if (C0) {
          if (c < split) C0[(size_t)R * split + c] = val;
          else           C1[(size_t)R * split + (c - split)] = val;
        }
      }
    }
  }
}

// 256 threads = 8 nodes x 32 lanes; each lane owns 4 channels (ushort4 = 8B bf16).
__global__ __launch_bounds__(256) void aggregate(
    const ushort4* __restrict__ hin, const int* __restrict__ row_ptr,
    const int2* __restrict__ csr, const float* __restrict__ dinv,
    const float4* __restrict__ bias4, ushort4* __restrict__ hout_bf,
    float4* __restrict__ hout_f4, int n, int do_relu, int scale_out) {
  int node = blockIdx.x * 8 + (threadIdx.x >> 5);
  if (node >= n) return;
  int t = threadIdx.x & 31;
  int beg = row_ptr[node], end = row_ptr[node + 1];
  ushort4 hs = hin[(size_t)node * 32 + t];   // self-loop (prescaled row)
  float4 acc = make_float4(bf2f(hs.x), bf2f(hs.y), bf2f(hs.z), bf2f(hs.w));
  int p = beg;
  for (; p + 4 <= end; p += 4) {
    int2 e0 = csr[p + 0];
    int2 e1 = csr[p + 1];
    int2 e2 = csr[p + 2];
    int2 e3 = csr[p + 3];
    ushort4 h0 = hin[(size_t)e0.x * 32 + t];
    ushort4 h1 = hin[(size_t)e1.x * 32 + t];
    ushort4 h2 = hin[(size_t)e2.x * 32 + t];
    ushort4 h3 = hin[(size_t)e3.x * 32 + t];
    float w0 = __int_as_float(e0.y), w1 = __int_as_float(e1.y);
    float w2 = __int_as_float(e2.y), w3 = __int_as_float(e3.y);
    acc.x = fmaf(w0, bf2f(h0.x), acc.x); acc.y = fmaf(w0, bf2f(h0.y), acc.y);
    acc.z = fmaf(w0, bf2f(h0.z), acc.z); acc.w = fmaf(w0, bf2f(h0.w), acc.w);
    acc.x = fmaf(w1, bf2f(h1.x), acc.x); acc.y = fmaf(w1, bf2f(h1.y), acc.y);
    acc.z = fmaf(w1, bf2f(h1.z), acc.z); acc.w = fmaf(w1, bf2f(h1.w), acc.w);
    acc.x = fmaf(w2, bf2f(h2.x), acc.x); acc.y = fmaf(w2, bf2f(h2.y), acc.y);
    acc.z = fmaf(w2, bf2f(h2.z), acc.z); acc.w = fmaf(w2, bf2f(h2.w), acc.w);
    acc.x = fmaf(w3, bf2f(h3.x), acc.x); acc.y = fmaf(w3, bf2f(h3.y), acc.y);
    acc.z = fmaf(w3, bf2f(h3.z), acc.z); acc.w = fmaf(w3, bf2f(h3.w), acc.w);
  }
  for (; p < end; ++p) {
    int2 e = csr[p];
    ushort4 hv = hin[(size_t)e.x * 32 + t];
    float wv = __int_as_float(e.y);
    acc.x = fmaf(wv, bf2f(hv.x), acc.x); acc.y = fmaf(wv, bf2f(hv.y), acc.y);
    acc.z = fmaf(wv, bf2f(hv.z), acc.z); acc.w = fmaf(wv, bf2f(hv.w), acc.w);
  }
  float dc = dinv[node];
  float4 val = make_float4(dc * acc.x, dc * acc.y, dc * acc.z, dc * acc.w);
  if (bias4) {
    float4 b = bias4[t];
    val.x += b.x; val.y += b.y; val.z += b.z; val.w += b.w;
  }
  if (do_relu) {
    val.x = fmaxf(val.x, 0.f); val.y = fmaxf(val.y, 0.f);
    val.z = fmaxf(val.z, 0.f); val.w = fmaxf(val.w, 0.f);
  }
  if (scale_out) {
    val.x *= dc; val.y *= dc; val.z *= dc; val.w *= dc;
  }
  size_t o = (size_t)node * 32 + t;
  if (hout_bf) {
    ushort4 ov;
    ov.x = f2bf_rne(val.x); ov.y = f2bf_rne(val.y);
    ov.z = f2bf_rne(val.z); ov.w = f2bf_rne(val.w);
    hout_bf[o] = ov;
  }
  if (hout_f4) hout_f4[o] = val;
}

extern "C" void kernel_launch(void* const* d_in, const int* in_sizes, int n_in,
                              void* d_out, int out_size, void* d_ws, size_t ws_size,
                              hipStream_t stream) {
  const float* x   = (const float*)d_in[0];
  const int*   ei  = (const int*)d_in[1];
  const float* ea  = (const float*)d_in[2];
  const float* W1  = (const float*)d_in[3];
  const float* b1  = (const float*)d_in[4];
  const float* Wmu = (const float*)d_in[5];
  const float* bmu = (const float*)d_in[6];
  const float* Wls = (const float*)d_in[7];
  const float* bls = (const float*)d_in[8];
  const int N = in_sizes[0] / 128;
  const int E = in_sizes[2];
  const int* row = ei;
  const int* col = ei + E;

  char* p = (char*)d_ws;
  auto alloc = [&](size_t bytes) -> void* {
    void* r = (void*)p;
    p += (bytes + 255) & ~(size_t)255;
    return r;
  };
  float* dinv    = (float*)alloc((size_t)N * 4);
  int*   row_ptr = (int*)alloc((size_t)(N + 1) * 4);
  unsigned short* w1t_hi = (unsigned short*)alloc(128 * 128 * 2);
  unsigned short* w1t_lo = (unsigned short*)alloc(128 * 128 * 2);
  unsigned short* wct_hi = (unsigned short*)alloc(128 * 128 * 2);
  unsigned short* wct_lo = (unsigned short*)alloc(128 * 128 * 2);
  float* bcat    = (float*)alloc(128 * 4);
  int2*  csr     = (int2*)alloc((size_t)E * 8);
  float* bufA    = (float*)alloc((size_t)N * 128 * 4);          // agg2 out (fp32)
  unsigned short* bufB = (unsigned short*)alloc((size_t)N * 128 * 2);  // hs1 bf16
  unsigned short* bufC = (unsigned short*)alloc((size_t)N * 128 * 2);  // out1 bf16

  // Aliased scratch (dead before its alias target is first written):
  //  - part (E int2 = 12.8MB) -> bufA   (bufA first written by agg2, much later)
  //  - G / tot / start        -> bufB   (bufB first written by gemm1, after build)
  int2* part  = (int2*)bufA;
  int*  G     = (int*)bufB;                       // 512*NBLK ints = 2MB max
  int*  tot   = (int*)((char*)bufB + (size_t)512 * NBLK * 4);
  int*  start = tot + 512;                        // nbuck+1 entries

  float* out_mu = (float*)d_out;
  float* out_ls = out_mu + (size_t)N * 64;

  const int nbuck = (N + 255) >> 8;               // 391 coarse buckets
  const int epb   = (E + NBLK - 1) / NBLK;        // edges per partition block
  int nbN = (N + 255) / 256;

  prep_wt<<<64, 256, 0, stream>>>(W1, w1t_hi, w1t_lo);
  prep_wcat_t<<<64, 256, 0, stream>>>(Wmu, Wls, bmu, bls, wct_hi, wct_lo, bcat);

  hist_coarse<<<NBLK, 256, 0, stream>>>(col, G, E, nbuck, epb);
  scan_bucket<<<nbuck, NBLK, 0, stream>>>(G, tot);
  scan_start<<<1, 512, 0, stream>>>(tot, start, row_ptr, nbuck, N, E);
  partition_edges<<<NBLK, 256, 0, stream>>>(row, col, ea, G, start, part,
                                            E, nbuck, epb);
  build_fine<<<nbuck, 256, 0, stream>>>(start, part, row_ptr, csr, N);
  deg_dinv<<<nbN, 256, 0, stream>>>(row_ptr, csr, dinv, N);

  int gblocks = (N + 127) / 128;
  int ablocks = (N + 7) / 8;
  // hs1 = (x @ W1) * dinv[row]  -> bf16 only
  gemm_mfma<<<gblocks, 256, 0, stream>>>(x, w1t_hi, w1t_lo, nullptr, dinv,
                                         nullptr, nullptr, bufB, 128, N);
  // out1 = dinv * relu(dinv[c]*(sum w*hs1[r] + hs1[c]) + b1) -> bf16 only
  aggregate<<<ablocks, 256, 0, stream>>>((const ushort4*)bufB, row_ptr, csr, dinv,
                                         (const float4*)b1, (ushort4*)bufC,
                                         nullptr, N, 1, 1);
  // agg2 = dinv[c]*(sum w*out1[r] + out1[c])  == A_norm @ h  -> fp32
  aggregate<<<ablocks, 256, 0, stream>>>((const ushort4*)bufC, row_ptr, csr, dinv,
                                         nullptr, nullptr, (float4*)bufA, N, 0, 0);
  // [mu | logstd] = agg2 @ [Wmu | Wls] + [bmu | bls]
  gemm_mfma<<<gblocks, 256, 0, stream>>>(bufA, wct_hi, wct_lo, bcat, nullptr,
                                         out_mu, out_ls, nullptr, 64, N);
}